// Round 1
// 342.031 us; speedup vs baseline: 1.0102x; 1.0102x over previous
//
#include <hip/hip_runtime.h>
#include <hip/hip_bf16.h>

// NATLayer fp32 I/O, bf16 internal. B=8, H=W=128, C=128, HEADS=4, d=32, K=7,
// N=16384 (1-D neighborhood over flattened N), M = B*N = 131072.
//
// Round 6: 2 dispatches (k1+k3 FUSED).
//  0. cvt_params: fp32 weights -> bf16 param block
//  1. k_fused (64 tokens/block, 80.1 KB LDS, 2 blocks/CU):
//     LN1 + QKV(MFMA) + attention + proj(MFMA) + x-resid + LN2
//     + fc1(MFMA) + gelu + fc2(MFMA, 256-wide K-halves) + x2-resid -> out
//     ys and x2 never touch global memory (stay in LDS).
//  LayerNorms use 16-lane-per-row mapping (8 ch/lane): dwordx4 loads,
//  4-level xor shuffle reduce, b128 LDS writes (was: 2 ch/lane, 6-level
//  reduce, b32 stores -> 6x fewer ds_bpermute, 10->3 global load iters).
// All C-layout LDS tiles use blk-XOR swizzle (key=(row>>2)&3) + pad-8 rows.

#define NPOS 16384
#define MROWS 131072

typedef unsigned short ushort_t;
typedef __bf16 bf8 __attribute__((ext_vector_type(8)));
typedef float f4 __attribute__((ext_vector_type(4)));

#define P_QKV_W 0
#define P_QKV_B 49152
#define P_PROJ_W 49536
#define P_PROJ_B 65920
#define P_FC1_W 66048
#define P_FC1_B 131584
#define P_FC2_W 132096
#define P_FC2_B 197632
#define P_TOTAL 197760

__device__ __forceinline__ float b2f(ushort_t u) {
    union { unsigned int i; float f; } v; v.i = ((unsigned int)u) << 16; return v.f;
}
__device__ __forceinline__ ushort_t f2b(float f) {
    __hip_bfloat16 h = __float2bfloat16(f);
    return *reinterpret_cast<ushort_t*>(&h);
}
// blk-XOR swizzled LDS address (shorts); key=(row>>2)&3, 8-short blocks.
__device__ __forceinline__ int swz(int row, int col, int stride) {
    return row * stride + ((((col >> 3) ^ ((row >> 2) & 3)) << 3) | (col & 7));
}
// stride-128 tile needs stronger key (row&7) since 128 shorts == 0 mod 32 banks
__device__ __forceinline__ int swz8(int row, int col) {
    return row * 128 + ((((col >> 3) ^ (row & 7)) << 3) | (col & 7));
}
__device__ __forceinline__ void ld8(const ushort_t* p, float* d) {
    uint4 pv = *(const uint4*)p;
    const ushort_t* us = (const ushort_t*)&pv;
    #pragma unroll
    for (int e = 0; e < 8; e++) d[e] = b2f(us[e]);
}
__device__ __forceinline__ void st8(ushort_t* p, const float* d) {
    unsigned int pk[4];
    #pragma unroll
    for (int e = 0; e < 4; e++)
        pk[e] = (unsigned int)f2b(d[2 * e]) | ((unsigned int)f2b(d[2 * e + 1]) << 16);
    *(uint4*)p = *(uint4*)pk;
}
__device__ __forceinline__ float fast_gelu(float x) {
    // tanh-form GELU, ~1e-3 abs err (below bf16 h quantization)
    float u = x * (0.7978845608f + 0.0356774081f * x * x);
    float t = 1.0f - 2.0f / (1.0f + __expf(2.0f * u));
    return 0.5f * x * (1.0f + t);
}

__global__ __launch_bounds__(256) void cvt_params(
    const float* __restrict__ qkv_w, const float* __restrict__ qkv_b,
    const float* __restrict__ proj_w, const float* __restrict__ proj_b,
    const float* __restrict__ fc1_w, const float* __restrict__ fc1_b,
    const float* __restrict__ fc2_w, const float* __restrict__ fc2_b,
    ushort_t* __restrict__ p)
{
    int i = blockIdx.x * 256 + threadIdx.x;
    if (i >= P_TOTAL) return;
    float v;
    if      (i < P_QKV_B)  v = qkv_w[i - P_QKV_W];
    else if (i < P_PROJ_W) v = qkv_b[i - P_QKV_B];
    else if (i < P_PROJ_B) v = proj_w[i - P_PROJ_W];
    else if (i < P_FC1_W)  v = proj_b[i - P_PROJ_B];
    else if (i < P_FC1_B)  v = fc1_w[i - P_FC1_W];
    else if (i < P_FC2_W)  v = fc1_b[i - P_FC1_B];
    else if (i < P_FC2_B)  v = fc2_w[i - P_FC2_W];
    else                   v = fc2_b[i - P_FC2_B];
    p[i] = f2b(v);
}

// ======== fused: LN1+QKV+attn+proj+resid+LN2+fc1+gelu+fc2+resid ============
// 64 tokens/block (+8 halo each side -> 80 rows), 512 threads.
// LDS shorts (40064 total = 80128 B -> 2 blocks/CU):
//   region A [0,10240):     xs[80][128] swz8; overlays: qo[64][136], ys[64][136]
//   region B [10240,31360): kv[80][264] swz;  overlay:  ct[64][136] (=x2)
//   region C [31360,40064): xres[64][136] swz
//   MLP:     h[64][264] at 18944..35840 (over dead kv-tail + xres)
__global__ __launch_bounds__(512, 2) void k_fused(
    const float* __restrict__ x, const float* __restrict__ n1w,
    const float* __restrict__ n1b, const ushort_t* __restrict__ qkvw,
    const float* __restrict__ qkvb, const float* __restrict__ rpb,
    const ushort_t* __restrict__ projw, const float* __restrict__ projb,
    const float* __restrict__ n2w, const float* __restrict__ n2b,
    const ushort_t* __restrict__ fc1w, const float* __restrict__ fc1b,
    const ushort_t* __restrict__ fc2w, const float* __restrict__ fc2b,
    float* __restrict__ out)
{
    extern __shared__ ushort_t sm[];
    ushort_t* xs   = sm;           // [80][128] swizzled (swz8)
    ushort_t* kv   = sm + 10240;   // [80][264] (swz)
    ushort_t* xres = sm + 31360;   // [64][136] (swz)
    ushort_t* qo   = sm;           // overlay: [64][136] (swz)
    ushort_t* ct   = sm + 10240;   // overlay: [64][136] (swz)  == x2
    ushort_t* ys   = sm;           // overlay: [64][136] (swz)  LN2 out
    ushort_t* h    = sm + 18944;   // overlay: [64][264] (swz)  gelu(fc1)

    int t0  = blockIdx.x * 64;
    int ib  = t0 & ~(NPOS - 1);
    int nl0 = t0 & (NPOS - 1);
    int tid = threadIdx.x;
    int w = tid >> 6, lane = tid & 63;
    int quad = lane >> 4, lrow = lane & 15;

    // ---- phase 1: LN1 of 80 rows (16 lanes/row, 8 ch/lane); park raw x too
    {
        int grp = tid >> 4, l = tid & 15;
        int c0 = l * 8;
        float4 wa = *(const float4*)&n1w[c0], wb = *(const float4*)&n1w[c0 + 4];
        float4 ba = *(const float4*)&n1b[c0], bb = *(const float4*)&n1b[c0 + 4];
        float w8[8] = {wa.x, wa.y, wa.z, wa.w, wb.x, wb.y, wb.z, wb.w};
        float b8[8] = {ba.x, ba.y, ba.z, ba.w, bb.x, bb.y, bb.z, bb.w};
        #pragma unroll
        for (int pass = 0; pass < 3; pass++) {
            int r = pass * 32 + grp;
            if (r < 80) {
                int nl = min(max(nl0 - 8 + r, 0), NPOS - 1);
                const float* xp = &x[(size_t)(ib + nl) * 128 + c0];
                float4 va = *(const float4*)xp;
                float4 vb = *(const float4*)(xp + 4);
                float v[8] = {va.x, va.y, va.z, va.w, vb.x, vb.y, vb.z, vb.w};
                float s = 0.f, s2 = 0.f;
                #pragma unroll
                for (int e = 0; e < 8; e++) { s += v[e]; s2 += v[e] * v[e]; }
                #pragma unroll
                for (int off = 8; off; off >>= 1) {
                    s  += __shfl_xor(s,  off, 64);
                    s2 += __shfl_xor(s2, off, 64);
                }
                float mu   = s * (1.0f / 128.0f);
                float rstd = rsqrtf(s2 * (1.0f / 128.0f) - mu * mu + 1e-5f);
                float o[8];
                #pragma unroll
                for (int e = 0; e < 8; e++) o[e] = (v[e] - mu) * rstd * w8[e] + b8[e];
                st8(&xs[swz8(r, c0)], o);
                if (r >= 8 && r < 72) st8(&xres[swz(r - 8, c0, 136)], v);
            }
        }
    }
    __syncthreads();

    // ---- phase 2: QKV GEMM. M=80 (5 tiles), N=384 (24 tiles, 3/wave)
    {
        f4 acc[5][3];
        #pragma unroll
        for (int i = 0; i < 5; i++)
            #pragma unroll
            for (int j = 0; j < 3; j++) { f4 z = {0.f,0.f,0.f,0.f}; acc[i][j] = z; }
        #pragma unroll
        for (int k0 = 0; k0 < 128; k0 += 32) {
            bf8 bv[3];
            #pragma unroll
            for (int jj = 0; jj < 3; jj++) {
                int n = (3 * w + jj) * 16 + lrow;
                bv[jj] = *(const bf8*)&qkvw[(size_t)n * 128 + k0 + quad * 8];
            }
            #pragma unroll
            for (int i = 0; i < 5; i++) {
                bf8 av = *(const bf8*)&xs[swz8(i * 16 + lrow, k0 + quad * 8)];
                #pragma unroll
                for (int jj = 0; jj < 3; jj++)
                    acc[i][jj] = __builtin_amdgcn_mfma_f32_16x16x32_bf16(
                        av, bv[jj], acc[i][jj], 0, 0, 0);
            }
        }
        __syncthreads();          // xs reads done before qo overlay writes
        #pragma unroll
        for (int jj = 0; jj < 3; jj++) {
            int jt = 3 * w + jj;
            int n = jt * 16 + lrow;
            float bj = qkvb[n];
            #pragma unroll
            for (int i = 0; i < 5; i++) {
                #pragma unroll
                for (int r = 0; r < 4; r++) {
                    int mrow = i * 16 + quad * 4 + r;
                    float v = acc[i][jj][r] + bj;
                    if (jt < 8) {
                        if (mrow >= 8 && mrow < 72)
                            qo[swz(mrow - 8, n, 136)] = f2b(v * 0.17677669529663687f);
                    } else {
                        kv[swz(mrow, n - 128, 264)] = f2b(v);
                    }
                }
            }
        }
    }
    __syncthreads();

    // ---- phase 3: attention. thread = (token=tid>>3, head=(tid>>1)&3, half=tid&1)
    {
        int t = tid >> 3, head = (tid >> 1) & 3, half = tid & 1;
        int n = nl0 + t;
        int s = n - 3;
        if (s < 0) s = 0;
        if (s > NPOS - 7) s = NPOS - 7;
        int r0 = s - nl0 + 8;
        int cb = head * 32 + half * 16;

        float q[16];
        ld8(&qo[swz(t, cb, 136)], q);
        ld8(&qo[swz(t, cb + 8, 136)], q + 8);

        float logit[7];
        #pragma unroll
        for (int j = 0; j < 7; j++) {
            int row = r0 + j;
            float kk[8];
            float p = 0.f;
            ld8(&kv[swz(row, cb, 264)], kk);
            #pragma unroll
            for (int e = 0; e < 8; e++) p += q[e] * kk[e];
            ld8(&kv[swz(row, cb + 8, 264)], kk);
            #pragma unroll
            for (int e = 0; e < 8; e++) p += q[8 + e] * kk[e];
            p += __shfl_xor(p, 1, 64);   // combine the two 16-chan halves
            logit[j] = p + rpb[head * 13 + (s + j - n + 6)];
        }
        float m = logit[0];
        #pragma unroll
        for (int j = 1; j < 7; j++) m = fmaxf(m, logit[j]);
        float e[7], esum = 0.f;
        #pragma unroll
        for (int j = 0; j < 7; j++) { e[j] = __expf(logit[j] - m); esum += e[j]; }
        float inv = 1.0f / esum;

        float o[16];
        #pragma unroll
        for (int c = 0; c < 16; c++) o[c] = 0.f;
        #pragma unroll
        for (int j = 0; j < 7; j++) {
            int row = r0 + j;
            float vv[8];
            float ej = e[j];
            ld8(&kv[swz(row, 128 + cb, 264)], vv);
            #pragma unroll
            for (int c = 0; c < 8; c++) o[c] += ej * vv[c];
            ld8(&kv[swz(row, 128 + cb + 8, 264)], vv);
            #pragma unroll
            for (int c = 0; c < 8; c++) o[8 + c] += ej * vv[c];
        }
        #pragma unroll
        for (int c = 0; c < 16; c++) o[c] *= inv;
        st8(&qo[swz(t, cb, 136)], o);
        st8(&qo[swz(t, cb + 8, 136)], o + 8);
    }
    __syncthreads();

    // ---- phase 4: proj (M=64, N=128; wave w owns N-tile w) + resid -> ct
    {
        int n = w * 16 + lrow;
        f4 acc2[4];
        #pragma unroll
        for (int i = 0; i < 4; i++) { f4 z = {0.f,0.f,0.f,0.f}; acc2[i] = z; }
        #pragma unroll
        for (int k0 = 0; k0 < 128; k0 += 32) {
            bf8 bv = *(const bf8*)&projw[(size_t)n * 128 + k0 + quad * 8];
            #pragma unroll
            for (int i = 0; i < 4; i++) {
                bf8 av = *(const bf8*)&qo[swz(i * 16 + lrow, k0 + quad * 8, 136)];
                acc2[i] = __builtin_amdgcn_mfma_f32_16x16x32_bf16(av, bv, acc2[i], 0, 0, 0);
            }
        }
        float bj = projb[n];
        #pragma unroll
        for (int i = 0; i < 4; i++) {
            #pragma unroll
            for (int r = 0; r < 4; r++) {
                int row = i * 16 + quad * 4 + r;
                float v = acc2[i][r] + bj + b2f(xres[swz(row, n, 136)]);
                ct[swz(row, n, 136)] = f2b(v);
            }
        }
    }
    __syncthreads();

    // ---- phase 5: LN2 (16 lanes/row) -> ys in LDS. No global traffic.
    {
        int grp = tid >> 4, l = tid & 15;
        int c0 = l * 8;
        float4 wa = *(const float4*)&n2w[c0], wb = *(const float4*)&n2w[c0 + 4];
        float4 ba = *(const float4*)&n2b[c0], bb = *(const float4*)&n2b[c0 + 4];
        float w8[8] = {wa.x, wa.y, wa.z, wa.w, wb.x, wb.y, wb.z, wb.w};
        float b8[8] = {ba.x, ba.y, ba.z, ba.w, bb.x, bb.y, bb.z, bb.w};
        #pragma unroll
        for (int pass = 0; pass < 2; pass++) {
            int t = pass * 32 + grp;
            float v[8];
            ld8(&ct[swz(t, c0, 136)], v);
            float s = 0.f, s2 = 0.f;
            #pragma unroll
            for (int e = 0; e < 8; e++) { s += v[e]; s2 += v[e] * v[e]; }
            #pragma unroll
            for (int off = 8; off; off >>= 1) {
                s  += __shfl_xor(s,  off, 64);
                s2 += __shfl_xor(s2, off, 64);
            }
            float mu   = s * (1.0f / 128.0f);
            float rstd = rsqrtf(s2 * (1.0f / 128.0f) - mu * mu + 1e-5f);
            float o[8];
            #pragma unroll
            for (int e = 0; e < 8; e++) o[e] = (v[e] - mu) * rstd * w8[e] + b8[e];
            st8(&ys[swz(t, c0, 136)], o);
        }
    }
    __syncthreads();

    // ---- phase 6: fc1 + gelu + fc2 (h by 256-wide K-halves) + x2 resid
    {
        f4 acc2[4];
        #pragma unroll
        for (int i = 0; i < 4; i++) { f4 z = {0.f,0.f,0.f,0.f}; acc2[i] = z; }
        int n = w * 16 + lrow;

        for (int hh = 0; hh < 2; hh++) {
            // fc1: local N=256 (16 tiles, 2/wave), K=128
            f4 acc[4][2];
            #pragma unroll
            for (int i = 0; i < 4; i++)
                #pragma unroll
                for (int j = 0; j < 2; j++) { f4 z = {0.f,0.f,0.f,0.f}; acc[i][j] = z; }
            #pragma unroll
            for (int k0 = 0; k0 < 128; k0 += 32) {
                bf8 bv[2];
                #pragma unroll
                for (int jj = 0; jj < 2; jj++) {
                    int frow = hh * 256 + (w * 2 + jj) * 16 + lrow;
                    bv[jj] = *(const bf8*)&fc1w[(size_t)frow * 128 + k0 + quad * 8];
                }
                #pragma unroll
                for (int i = 0; i < 4; i++) {
                    bf8 av = *(const bf8*)&ys[swz(i * 16 + lrow, k0 + quad * 8, 136)];
                    #pragma unroll
                    for (int jj = 0; jj < 2; jj++)
                        acc[i][jj] = __builtin_amdgcn_mfma_f32_16x16x32_bf16(
                            av, bv[jj], acc[i][jj], 0, 0, 0);
                }
            }
            __syncthreads();   // prior fc2 half done reading h before overwrite
            #pragma unroll
            for (int jj = 0; jj < 2; jj++) {
                int cb = (w * 2 + jj) * 16 + lrow;        // local col 0..255
                float bj = fc1b[hh * 256 + cb];
                #pragma unroll
                for (int i = 0; i < 4; i++) {
                    #pragma unroll
                    for (int r = 0; r < 4; r++) {
                        int row = i * 16 + quad * 4 + r;
                        h[swz(row, cb, 264)] = f2b(fast_gelu(acc[i][jj][r] + bj));
                    }
                }
            }
            __syncthreads();
            // fc2 partial: K-half 256
            #pragma unroll
            for (int k0 = 0; k0 < 256; k0 += 32) {
                bf8 bv = *(const bf8*)&fc2w[(size_t)n * 512 + hh * 256 + k0 + quad * 8];
                #pragma unroll
                for (int i = 0; i < 4; i++) {
                    bf8 av = *(const bf8*)&h[swz(i * 16 + lrow, k0 + quad * 8, 264)];
                    acc2[i] = __builtin_amdgcn_mfma_f32_16x16x32_bf16(av, bv, acc2[i], 0, 0, 0);
                }
            }
        }

        float bj = fc2b[n];
        #pragma unroll
        for (int i = 0; i < 4; i++) {
            #pragma unroll
            for (int r = 0; r < 4; r++) {
                int row = i * 16 + quad * 4 + r;
                out[(size_t)(t0 + row) * 128 + n] =
                    acc2[i][r] + bj + b2f(ct[swz(row, n, 136)]);
            }
        }
    }
}

extern "C" void kernel_launch(void* const* d_in, const int* in_sizes, int n_in,
                              void* d_out, int out_size, void* d_ws, size_t ws_size,
                              hipStream_t stream) {
    const float* x      = (const float*)d_in[0];
    const float* n1w    = (const float*)d_in[1];
    const float* n1b    = (const float*)d_in[2];
    const float* qkv_w  = (const float*)d_in[3];
    const float* qkv_b  = (const float*)d_in[4];
    const float* rpb    = (const float*)d_in[5];
    const float* proj_w = (const float*)d_in[6];
    const float* proj_b = (const float*)d_in[7];
    const float* n2w    = (const float*)d_in[8];
    const float* n2b    = (const float*)d_in[9];
    const float* fc1_w  = (const float*)d_in[10];
    const float* fc1_b  = (const float*)d_in[11];
    const float* fc2_w  = (const float*)d_in[12];
    const float* fc2_b  = (const float*)d_in[13];

    ushort_t* params = (ushort_t*)d_ws;
    float*    outf   = (float*)d_out;

    cvt_params<<<(P_TOTAL + 255) / 256, 256, 0, stream>>>(
        qkv_w, qkv_b, proj_w, proj_b, fc1_w, fc1_b, fc2_w, fc2_b, params);

    k_fused<<<MROWS / 64, 512, 80128, stream>>>(
        x, n1w, n1b, params + P_QKV_W, qkv_b, rpb,
        params + P_PROJ_W, proj_b, n2w, n2b,
        params + P_FC1_W, fc1_b, params + P_FC2_W, fc2_b, outf);
}